// Round 3
// baseline (4302.015 us; speedup 1.0000x reference)
//
#include <hip/hip_runtime.h>
#include <hip/hip_bf16.h>

#define Bc   64
#define Cc   256
#define Nn   2304
#define NHh  8
#define DFFf 512
#define Mm   64
#define NT   16
#define NTILES 144   // 2304 / 16

// ---------------------------------------------------------------------------
// K/V precompute: K[c][m] = wk[c,:]·bcw[m,:] + bk[c]  (kv input is bcw^T bcast)
// ---------------------------------------------------------------------------
__global__ void kv_kernel(const float* __restrict__ wk, const float* __restrict__ bk,
                          const float* __restrict__ wv, const float* __restrict__ bv,
                          const float* __restrict__ bcw,
                          float* __restrict__ Kout, float* __restrict__ Vout) {
    int c = blockIdx.x;      // 256 blocks
    int m = threadIdx.x;     // 64 threads
    const float* wkr = wk + c * Cc;
    const float* wvr = wv + c * Cc;
    const float* br  = bcw + m * Cc;
    float aK = 0.f, aV = 0.f;
    #pragma unroll 8
    for (int i = 0; i < Cc; ++i) {
        float bcv = br[i];
        aK = fmaf(wkr[i], bcv, aK);
        aV = fmaf(wvr[i], bcv, aV);
    }
    Kout[c * Mm + m] = aK + bk[c];
    Vout[c * Mm + m] = aV + bv[c];
}

// ---------------------------------------------------------------------------
// GEMM helpers: one output row (16 cols) per thread, activations from LDS
// (broadcast float4 reads), weight row streamed from global (L2-resident).
// ---------------------------------------------------------------------------
__device__ __forceinline__ void rowGemm(const float* __restrict__ src,
                                        const float* __restrict__ Wr, int K,
                                        float4 A[4]) {
    #pragma unroll
    for (int q = 0; q < 4; ++q) A[q] = make_float4(0.f, 0.f, 0.f, 0.f);
    #pragma unroll 4
    for (int k = 0; k < K; ++k) {
        float w = Wr[k];
        const float4* fr = (const float4*)(src + k * NT);
        #pragma unroll
        for (int q = 0; q < 4; ++q) {
            float4 f = fr[q];
            A[q].x = fmaf(w, f.x, A[q].x);
            A[q].y = fmaf(w, f.y, A[q].y);
            A[q].z = fmaf(w, f.z, A[q].z);
            A[q].w = fmaf(w, f.w, A[q].w);
        }
    }
}

__device__ __forceinline__ void rowGemmDual(const float* __restrict__ src,
                                            const float* __restrict__ W0r,
                                            const float* __restrict__ W1r, int K,
                                            float4 A[4], float4 Bv[4]) {
    #pragma unroll
    for (int q = 0; q < 4; ++q) {
        A[q]  = make_float4(0.f, 0.f, 0.f, 0.f);
        Bv[q] = make_float4(0.f, 0.f, 0.f, 0.f);
    }
    #pragma unroll 4
    for (int k = 0; k < K; ++k) {
        float w0 = W0r[k];
        float w1 = W1r[k];
        const float4* fr = (const float4*)(src + k * NT);
        #pragma unroll
        for (int q = 0; q < 4; ++q) {
            float4 f = fr[q];
            A[q].x  = fmaf(w0, f.x, A[q].x);
            A[q].y  = fmaf(w0, f.y, A[q].y);
            A[q].z  = fmaf(w0, f.z, A[q].z);
            A[q].w  = fmaf(w0, f.w, A[q].w);
            Bv[q].x = fmaf(w1, f.x, Bv[q].x);
            Bv[q].y = fmaf(w1, f.y, Bv[q].y);
            Bv[q].z = fmaf(w1, f.z, Bv[q].z);
            Bv[q].w = fmaf(w1, f.w, Bv[q].w);
        }
    }
}

// ---------------------------------------------------------------------------
// Fully fused SFTA: one block per (batch b, 16-wide n tile).
// ---------------------------------------------------------------------------
__global__ __launch_bounds__(256) void sfta_fused(
    const float* __restrict__ feat,
    const float* __restrict__ Kw, const float* __restrict__ Vw,
    const float* __restrict__ wq, const float* __restrict__ bq,
    const float* __restrict__ wm, const float* __restrict__ bm,
    const float* __restrict__ w1, const float* __restrict__ b1,
    const float* __restrict__ w2, const float* __restrict__ b2,
    const float* __restrict__ gam, const float* __restrict__ bet,
    float* __restrict__ out) {
    __shared__ __align__(16) float sF[Cc * NT];    // feat -> out(scaled) -> src
    __shared__ __align__(16) float sQ[Cc * NT];    // q -> x
    __shared__ __align__(16) float sS[DFFf * NT];  // scores[h][m][j] -> merged -> h1
    __shared__ __align__(16) float sRed[3 * 256];  // block reductions
    __shared__ float sA[NT], sB[NT];               // scale / mu / rstd

    const int b  = blockIdx.y;
    const int n0 = blockIdx.x * NT;
    const int t  = threadIdx.x;
    const size_t baseF = (size_t)b * Cc * Nn + n0;

    // ---- 1. load feature tile [256 c][16 j] ----
    for (int idx = t; idx < Cc * NT; idx += 256) {
        int c = idx >> 4, j = idx & 15;
        sF[idx] = feat[baseF + (size_t)c * Nn + j];
    }
    __syncthreads();

    // ---- 2. q projection: sQ[c][j] = wq[c,:]·feat[:,j] + bq[c] ----
    {
        float4 A[4];
        rowGemm(sF, wq + t * Cc, Cc, A);
        float bb = bq[t];
        float4* dst = (float4*)(sQ + t * NT);
        #pragma unroll
        for (int q = 0; q < 4; ++q)
            dst[q] = make_float4(A[q].x + bb, A[q].y + bb, A[q].z + bb, A[q].w + bb);
    }
    __syncthreads();

    // ---- 3. scores + softmax (per (h,j) pair; channel o = d*8+h) ----
    if (t < 128) {
        const int h = t >> 4, j = t & 15;
        const float scl = 0.17677669529663687f;  // 1/sqrt(32)
        for (int mt = 0; mt < 4; ++mt) {
            float s[16];
            #pragma unroll
            for (int mm = 0; mm < 16; ++mm) s[mm] = 0.f;
            for (int d = 0; d < 32; ++d) {
                int c = d * NHh + h;
                float qv = sQ[c * NT + j];
                const float4* Kr = (const float4*)(Kw + c * Mm + mt * 16);
                #pragma unroll
                for (int q4 = 0; q4 < 4; ++q4) {
                    float4 kf = Kr[q4];
                    s[q4 * 4 + 0] = fmaf(qv, kf.x, s[q4 * 4 + 0]);
                    s[q4 * 4 + 1] = fmaf(qv, kf.y, s[q4 * 4 + 1]);
                    s[q4 * 4 + 2] = fmaf(qv, kf.z, s[q4 * 4 + 2]);
                    s[q4 * 4 + 3] = fmaf(qv, kf.w, s[q4 * 4 + 3]);
                }
            }
            #pragma unroll
            for (int mm = 0; mm < 16; ++mm)
                sS[(h * Mm + mt * 16 + mm) * NT + j] = s[mm] * scl;
        }
        // softmax over m for this (h, j)
        float mx = -1e30f;
        for (int m = 0; m < Mm; ++m) mx = fmaxf(mx, sS[(h * Mm + m) * NT + j]);
        float sum = 0.f;
        for (int m = 0; m < Mm; ++m) {
            float e = __expf(sS[(h * Mm + m) * NT + j] - mx);
            sS[(h * Mm + m) * NT + j] = e;
            sum += e;
        }
        float inv = 1.f / sum;
        for (int m = 0; m < Mm; ++m) sS[(h * Mm + m) * NT + j] *= inv;
    }
    __syncthreads();

    // ---- 4. PV: x[c][j] = sum_m prob[h][m][j] * V[c][m]  (h = c&7) ----
    {
        const int c = t, h = t & 7;
        float4 X[4];
        #pragma unroll
        for (int q = 0; q < 4; ++q) X[q] = make_float4(0.f, 0.f, 0.f, 0.f);
        const float* Vr = Vw + c * Mm;
        for (int m = 0; m < Mm; ++m) {
            float vv = Vr[m];
            const float4* pr = (const float4*)(sS + (h * Mm + m) * NT);
            #pragma unroll
            for (int q = 0; q < 4; ++q) {
                float4 p = pr[q];
                X[q].x = fmaf(vv, p.x, X[q].x);
                X[q].y = fmaf(vv, p.y, X[q].y);
                X[q].z = fmaf(vv, p.z, X[q].z);
                X[q].w = fmaf(vv, p.w, X[q].w);
            }
        }
        float4* dst = (float4*)(sQ + c * NT);   // overwrite q (dead)
        #pragma unroll
        for (int q = 0; q < 4; ++q) dst[q] = X[q];
    }
    __syncthreads();

    // ---- 5. merge projection: merged[c][j] -> sS[0..4096) ----
    {
        float4 A[4];
        rowGemm(sQ, wm + t * Cc, Cc, A);
        float bb = bm[t];
        float4* dst = (float4*)(sS + t * NT);
        #pragma unroll
        for (int q = 0; q < 4; ++q)
            dst[q] = make_float4(A[q].x + bb, A[q].y + bb, A[q].z + bb, A[q].w + bb);
    }
    __syncthreads();

    // ---- 6. cosine re-weighting: out[c][j] = feat[c][j]*(cos[j]+1) ----
    {
        const int grp = t >> 4, j = t & 15;
        float pmf = 0.f, pmm = 0.f, pff = 0.f;
        #pragma unroll
        for (int i = 0; i < 16; ++i) {
            int c = grp * 16 + i;
            float mv = sS[c * NT + j];
            float fv = sF[c * NT + j];
            pmf = fmaf(mv, fv, pmf);
            pmm = fmaf(mv, mv, pmm);
            pff = fmaf(fv, fv, pff);
        }
        sRed[grp * 16 + j]       = pmf;
        sRed[256 + grp * 16 + j] = pmm;
        sRed[512 + grp * 16 + j] = pff;
    }
    __syncthreads();
    if (t < 16) {
        float mf = 0.f, mm2 = 0.f, ff = 0.f;
        for (int g = 0; g < 16; ++g) {
            mf  += sRed[g * 16 + t];
            mm2 += sRed[256 + g * 16 + t];
            ff  += sRed[512 + g * 16 + t];
        }
        float cosv = mf / ((sqrtf(mm2) + 1e-5f) * (sqrtf(ff) + 1e-5f));
        sA[t] = cosv + 1.f;
    }
    __syncthreads();
    {
        float* fr = sF + t * NT;
        #pragma unroll
        for (int j = 0; j < 16; ++j) fr[j] *= sA[j];
    }
    __syncthreads();

    // ---- 7. FFN h1 = relu(w1·out + b1): rows t and t+256 -> sS[0..8192) ----
    {
        float4 A[4], Bv[4];
        rowGemmDual(sF, w1 + t * Cc, w1 + (t + 256) * Cc, Cc, A, Bv);
        float bb0 = b1[t], bb1 = b1[t + 256];
        float4* d0 = (float4*)(sS + t * NT);
        float4* d1 = (float4*)(sS + (t + 256) * NT);
        #pragma unroll
        for (int q = 0; q < 4; ++q) {
            d0[q] = make_float4(fmaxf(A[q].x + bb0, 0.f), fmaxf(A[q].y + bb0, 0.f),
                                fmaxf(A[q].z + bb0, 0.f), fmaxf(A[q].w + bb0, 0.f));
            d1[q] = make_float4(fmaxf(Bv[q].x + bb1, 0.f), fmaxf(Bv[q].y + bb1, 0.f),
                                fmaxf(Bv[q].z + bb1, 0.f), fmaxf(Bv[q].w + bb1, 0.f));
        }
    }
    __syncthreads();

    // ---- 8. src2 = w2·h1 + b2; src = out + src2 (into sF) ----
    {
        float4 A[4];
        rowGemm(sS, w2 + t * DFFf, DFFf, A);
        float bb = b2[t];
        float* fr = sF + t * NT;
        #pragma unroll
        for (int q = 0; q < 4; ++q) {
            fr[q * 4 + 0] += A[q].x + bb;
            fr[q * 4 + 1] += A[q].y + bb;
            fr[q * 4 + 2] += A[q].z + bb;
            fr[q * 4 + 3] += A[q].w + bb;
        }
    }
    __syncthreads();

    // ---- 9. LayerNorm over c, write transposed fp32 output ----
    {
        const int grp = t >> 4, j = t & 15;
        float ps = 0.f, pq = 0.f;
        #pragma unroll
        for (int i = 0; i < 16; ++i) {
            float v = sF[(grp * 16 + i) * NT + j];
            ps += v;
            pq = fmaf(v, v, pq);
        }
        sRed[grp * 16 + j]       = ps;
        sRed[256 + grp * 16 + j] = pq;
    }
    __syncthreads();
    if (t < 16) {
        float s = 0.f, q = 0.f;
        for (int g = 0; g < 16; ++g) {
            s += sRed[g * 16 + t];
            q += sRed[256 + g * 16 + t];
        }
        float mu  = s * (1.f / 256.f);
        float var = q * (1.f / 256.f) - mu * mu;
        sA[t] = mu;
        sB[t] = rsqrtf(var + 1e-5f);
    }
    __syncthreads();
    {
        float g  = gam[t];
        float be = bet[t];
        const float* fr = sF + t * NT;
        float* orow = out + baseF + (size_t)t * Nn;
        #pragma unroll
        for (int j = 0; j < 16; ++j) {
            float y = (fr[j] - sA[j]) * sB[j] * g + be;
            orow[j] = y;
        }
    }
}

// ---------------------------------------------------------------------------
extern "C" void kernel_launch(void* const* d_in, const int* in_sizes, int n_in,
                              void* d_out, int out_size, void* d_ws, size_t ws_size,
                              hipStream_t stream) {
    const float* feature = (const float*)d_in[0];
    const float* bcw     = (const float*)d_in[1];
    const float* wq = (const float*)d_in[2];  const float* bq = (const float*)d_in[3];
    const float* wk = (const float*)d_in[4];  const float* bk = (const float*)d_in[5];
    const float* wv = (const float*)d_in[6];  const float* bv = (const float*)d_in[7];
    const float* wm = (const float*)d_in[8];  const float* bm = (const float*)d_in[9];
    const float* w1 = (const float*)d_in[10]; const float* b1 = (const float*)d_in[11];
    const float* w2 = (const float*)d_in[12]; const float* b2 = (const float*)d_in[13];
    const float* gm = (const float*)d_in[14]; const float* bt = (const float*)d_in[15];

    float* Kw = (float*)d_ws;          // [256][64] fp32
    float* Vw = Kw + Cc * Mm;          // [256][64] fp32  (total 128 KB of ws)
    float* op = (float*)d_out;         // fp32 output per reference dtype

    hipLaunchKernelGGL(kv_kernel, dim3(Cc), dim3(Mm), 0, stream,
                       wk, bk, wv, bv, bcw, Kw, Vw);
    hipLaunchKernelGGL(sfta_fused, dim3(NTILES, Bc), dim3(256), 0, stream,
                       feature, Kw, Vw, wq, bq, wm, bm, w1, b1, w2, b2, gm, bt, op);
}

// Round 4
// 914.207 us; speedup vs baseline: 4.7057x; 4.7057x over previous
//
#include <hip/hip_runtime.h>

#define Bc   64
#define Cc   256
#define Nn   2304
#define DFFf 512
#define Mm   64
#define NTILE 64
#define NTB   36   // 2304/64

typedef __bf16 bf16_t;
typedef __bf16 bf16x8 __attribute__((ext_vector_type(8)));
typedef __bf16 bf16x4 __attribute__((ext_vector_type(4)));
typedef float  f32x4  __attribute__((ext_vector_type(4)));

__device__ __forceinline__ bf16_t cvt(float f) { return (bf16_t)f; }

__device__ __forceinline__ f32x4 mfma16(bf16x8 a, bf16x8 b, f32x4 c) {
    return __builtin_amdgcn_mfma_f32_16x16x32_bf16(a, b, c, 0, 0, 0);
}

// ---------------------------------------------------------------------------
// K/V precompute (fp32): K[c][m] = wk[c,:]·bcw[m,:] + bk[c]
// ---------------------------------------------------------------------------
__global__ void kv_kernel(const float* __restrict__ wk, const float* __restrict__ bk,
                          const float* __restrict__ wv, const float* __restrict__ bv,
                          const float* __restrict__ bcw,
                          float* __restrict__ Kout, float* __restrict__ Vout) {
    int c = blockIdx.x;      // 256
    int m = threadIdx.x;     // 64
    const float* wkr = wk + c * Cc;
    const float* wvr = wv + c * Cc;
    const float* br  = bcw + m * Cc;
    float aK = 0.f, aV = 0.f;
    #pragma unroll 8
    for (int i = 0; i < Cc; ++i) {
        float bcv = br[i];
        aK = fmaf(wkr[i], bcv, aK);
        aV = fmaf(wvr[i], bcv, aV);
    }
    Kout[c * Mm + m] = aK + bk[c];
    Vout[c * Mm + m] = aV + bv[c];
}

// ---------------------------------------------------------------------------
// Pack weights into MFMA A-fragment order (bf16), with head-permutations:
//  wqf : rows permuted so q output channel index is hd = h*32+d
//  wmf : cols permuted so k index is hd (consumes x stored [n][hd])
//  Kf  : scores B-operand frags per (h, m-tile)
//  Vf  : PV A-operand frags per (h, d-tile, m-kstep)
//  bqp : bq permuted to hd order
// Fragment element for A[M][K]: [rt][ks][lane][j] = A[rt*16+(lane&15)][ks*32+(lane>>4)*8+j]
// ---------------------------------------------------------------------------
__global__ void pack_kernel(const float* __restrict__ wq, const float* __restrict__ bq,
                            const float* __restrict__ wm, const float* __restrict__ w1,
                            const float* __restrict__ w2,
                            const float* __restrict__ Kf32, const float* __restrict__ Vf32,
                            bf16_t* __restrict__ wqf, bf16_t* __restrict__ wmf,
                            bf16_t* __restrict__ w1f, bf16_t* __restrict__ w2f,
                            bf16_t* __restrict__ Kf, bf16_t* __restrict__ Vf,
                            float* __restrict__ bqp) {
    int idx = blockIdx.x * 256 + threadIdx.x;
    if (idx < 65536) {                       // wqf: 16rt x 8ks, row-permuted
        int e = idx;
        int j = e & 7, lane = (e >> 3) & 63, rs = e >> 9;
        int ks = rs & 7, rt = rs >> 3;
        int op = rt * 16 + (lane & 15);           // hd = h*32+d
        int k  = ks * 32 + (lane >> 4) * 8 + j;
        int c  = (op & 31) * 8 + (op >> 5);       // c = d*8+h
        wqf[e] = cvt(wq[c * 256 + k]);
    } else if (idx < 131072) {               // wmf: col-permuted
        int e = idx - 65536;
        int j = e & 7, lane = (e >> 3) & 63, rs = e >> 9;
        int ks = rs & 7, rt = rs >> 3;
        int o = rt * 16 + (lane & 15);
        int k = ks * 32 + (lane >> 4) * 8 + j;    // hd
        int c = (k & 31) * 8 + (k >> 5);
        wmf[e] = cvt(wm[o * 256 + c]);
    } else if (idx < 262144) {               // w1f: 32rt x 8ks plain
        int e = idx - 131072;
        int j = e & 7, lane = (e >> 3) & 63, rs = e >> 9;
        int ks = rs & 7, rt = rs >> 3;
        w1f[e] = cvt(w1[(rt * 16 + (lane & 15)) * 256 + ks * 32 + (lane >> 4) * 8 + j]);
    } else if (idx < 393216) {               // w2f: 16rt x 16ks plain (K=512)
        int e = idx - 262144;
        int j = e & 7, lane = (e >> 3) & 63, rs = e >> 9;
        int ks = rs & 15, rt = rs >> 4;
        w2f[e] = cvt(w2[(rt * 16 + (lane & 15)) * 512 + ks * 32 + (lane >> 4) * 8 + j]);
    } else if (idx < 409600) {               // Kf: [h][mt] B-frag: B[d][m]=K[d*8+h][m]
        int e = idx - 393216;
        int j = e & 7, lane = (e >> 3) & 63, hm = e >> 9;
        int mt = hm & 3, h = hm >> 2;
        int d = (lane >> 4) * 8 + j, m = mt * 16 + (lane & 15);
        Kf[e] = cvt(Kf32[(d * 8 + h) * 64 + m]);
    } else if (idx < 425984) {               // Vf: [h][rt][ks] A-frag: A[d][m]=V[d*8+h][m]
        int e = idx - 409600;
        int j = e & 7, lane = (e >> 3) & 63, x = e >> 9;
        int ks = x & 1, rt = (x >> 1) & 1, h = x >> 2;
        int d = rt * 16 + (lane & 15), m = ks * 32 + (lane >> 4) * 8 + j;
        Vf[e] = cvt(Vf32[(d * 8 + h) * 64 + m]);
    } else if (idx < 426240) {               // bqp
        int op = idx - 425984;
        int c = (op & 31) * 8 + (op >> 5);
        bqp[op] = bq[c];
    }
}

// ---------------------------------------------------------------------------
// Fused SFTA with MFMA. One block per (batch, 64-col n-tile); wave w owns
// n-columns w*16..w*16+15. After the single staging barrier, all work is
// wave-private (LDS regions partitioned by n-row).
// ---------------------------------------------------------------------------
__global__ __launch_bounds__(256, 2) void sfta_mfma(
    const float* __restrict__ feat,
    const bf16_t* __restrict__ wqf, const float* __restrict__ bqp,
    const bf16_t* __restrict__ wmf, const float* __restrict__ bm,
    const bf16_t* __restrict__ w1f, const float* __restrict__ b1,
    const bf16_t* __restrict__ w2f, const float* __restrict__ b2,
    const bf16_t* __restrict__ Kf,  const bf16_t* __restrict__ Vf,
    const float* __restrict__ gam,  const float* __restrict__ bet,
    float* __restrict__ out) {
    // stride 264 (mult of 8 -> 16B-aligned rows, 2-way max bank aliasing = free)
    __shared__ __align__(16) bf16_t sFeat[64 * 264];   // [n][c] feat -> rescaled out
    __shared__ __align__(16) bf16_t sQX[64 * 264];     // [n][hd]: q, overwritten by x per head
    __shared__ __align__(16) bf16_t sP[4][16 * 72];    // per-wave: prob / ffn h1 stage

    const int t    = threadIdx.x;
    const int wid  = t >> 6;
    const int lane = t & 63;
    const int quad = lane >> 4;
    const int lid  = lane & 15;
    const int b    = blockIdx.y;
    const int n0   = blockIdx.x * NTILE;
    const size_t baseF = (size_t)b * Cc * Nn + n0;

    // ---- stage feature tile: global [c][n] fp32 -> LDS [n][c] bf16 ----
    {
        int cb = t >> 4;            // 0..15
        int nb = (t & 15) * 4;      // 0..60
        for (int i = 0; i < 16; ++i) {
            int c = i * 16 + cb;
            const float4 f4 = *(const float4*)(feat + baseF + (size_t)c * Nn + nb);
            sFeat[(nb + 0) * 264 + c] = cvt(f4.x);
            sFeat[(nb + 1) * 264 + c] = cvt(f4.y);
            sFeat[(nb + 2) * 264 + c] = cvt(f4.z);
            sFeat[(nb + 3) * 264 + c] = cvt(f4.w);
        }
    }
    __syncthreads();

    const int row = wid * 16 + lid;          // this lane's n-row
    bf16_t* frow = sFeat + row * 264;
    bf16_t* xrow = sQX  + row * 264;
    bf16_t* pw   = sP[wid];

    // ---- Q projection: D[hd][n] (rows pre-permuted via wqf) ----
    {
        bf16x8 bfr[8];
        #pragma unroll
        for (int ks = 0; ks < 8; ++ks)
            bfr[ks] = *(const bf16x8*)(frow + ks * 32 + quad * 8);
        #pragma unroll
        for (int rt = 0; rt < 16; ++rt) {
            f32x4 acc = {0.f, 0.f, 0.f, 0.f};
            #pragma unroll
            for (int ks = 0; ks < 8; ++ks) {
                bf16x8 a = *(const bf16x8*)(wqf + ((rt * 8 + ks) * 64 + lane) * 8);
                acc = mfma16(a, bfr[ks], acc);
            }
            int ob = rt * 16 + quad * 4;
            bf16x4 o;
            #pragma unroll
            for (int r = 0; r < 4; ++r) o[r] = cvt(acc[r] + bqp[ob + r]);
            *(bf16x4*)(xrow + ob) = o;
        }
    }

    // ---- attention per head: scores MFMA -> shuffle softmax -> PV MFMA ----
    const float scl = 0.17677669529663687f;  // 1/sqrt(32)
    #pragma unroll 1
    for (int h = 0; h < 8; ++h) {
        bf16x8 aq = *(const bf16x8*)(xrow + h * 32 + quad * 8);  // A[n][d]
        f32x4 sc[4];
        #pragma unroll
        for (int mt = 0; mt < 4; ++mt) {
            bf16x8 kb = *(const bf16x8*)(Kf + ((h * 4 + mt) * 64 + lane) * 8);
            f32x4 z = {0.f, 0.f, 0.f, 0.f};
            sc[mt] = mfma16(aq, kb, z);      // D[n-row][m-col]
        }
        float p[4][4];
        #pragma unroll
        for (int r = 0; r < 4; ++r) {        // softmax over m for row n=quad*4+r
            float v0 = sc[0][r] * scl, v1 = sc[1][r] * scl;
            float v2 = sc[2][r] * scl, v3 = sc[3][r] * scl;
            float mx = fmaxf(fmaxf(v0, v1), fmaxf(v2, v3));
            mx = fmaxf(mx, __shfl_xor(mx, 1));
            mx = fmaxf(mx, __shfl_xor(mx, 2));
            mx = fmaxf(mx, __shfl_xor(mx, 4));
            mx = fmaxf(mx, __shfl_xor(mx, 8));
            v0 = __expf(v0 - mx); v1 = __expf(v1 - mx);
            v2 = __expf(v2 - mx); v3 = __expf(v3 - mx);
            float s = v0 + v1 + v2 + v3;
            s += __shfl_xor(s, 1); s += __shfl_xor(s, 2);
            s += __shfl_xor(s, 4); s += __shfl_xor(s, 8);
            float inv = 1.f / s;
            p[0][r] = v0 * inv; p[1][r] = v1 * inv;
            p[2][r] = v2 * inv; p[3][r] = v3 * inv;
        }
        #pragma unroll
        for (int mt = 0; mt < 4; ++mt)
            #pragma unroll
            for (int r = 0; r < 4; ++r)
                pw[(quad * 4 + r) * 72 + mt * 16 + lid] = cvt(p[mt][r]);
        #pragma unroll
        for (int rt = 0; rt < 2; ++rt) {     // PV: D[d][n]
            f32x4 x = {0.f, 0.f, 0.f, 0.f};
            #pragma unroll
            for (int ks = 0; ks < 2; ++ks) {
                bf16x8 a  = *(const bf16x8*)(Vf + (((h * 2 + rt) * 2 + ks) * 64 + lane) * 8);
                bf16x8 bp = *(const bf16x8*)(pw + lid * 72 + ks * 32 + quad * 8);
                x = mfma16(a, bp, x);
            }
            int ob = h * 32 + rt * 16 + quad * 4;
            bf16x4 o;
            #pragma unroll
            for (int r = 0; r < 4; ++r) o[r] = cvt(x[r]);
            *(bf16x4*)(xrow + ob) = o;       // overwrite q_h (dead)
        }
    }

    // ---- merge GEMM (cols pre-permuted) + in-register cosine reduction ----
    float pmf = 0.f, pmm = 0.f, pff = 0.f;
    {
        bf16x8 bx[8];
        #pragma unroll
        for (int ks = 0; ks < 8; ++ks)
            bx[ks] = *(const bf16x8*)(xrow + ks * 32 + quad * 8);
        #pragma unroll
        for (int rt = 0; rt < 16; ++rt) {
            f32x4 acc = {0.f, 0.f, 0.f, 0.f};
            #pragma unroll
            for (int ks = 0; ks < 8; ++ks) {
                bf16x8 a = *(const bf16x8*)(wmf + ((rt * 8 + ks) * 64 + lane) * 8);
                acc = mfma16(a, bx[ks], acc);
            }
            int ob = rt * 16 + quad * 4;
            #pragma unroll
            for (int r = 0; r < 4; ++r) {
                float m = acc[r] + bm[ob + r];
                float f = (float)frow[ob + r];
                pmf = fmaf(m, f, pmf);
                pmm = fmaf(m, m, pmm);
                pff = fmaf(f, f, pff);
            }
        }
    }
    pmf += __shfl_xor(pmf, 16); pmf += __shfl_xor(pmf, 32);
    pmm += __shfl_xor(pmm, 16); pmm += __shfl_xor(pmm, 32);
    pff += __shfl_xor(pff, 16); pff += __shfl_xor(pff, 32);
    float scale = pmf / ((sqrtf(pmm) + 1e-5f) * (sqrtf(pff) + 1e-5f)) + 1.f;

    // ---- rescale feat row in place (each quad owns 64 channels) ----
    #pragma unroll
    for (int i = 0; i < 8; ++i) {
        bf16x8* pp = (bf16x8*)(frow + quad * 64 + i * 8);
        bf16x8 v = *pp;
        #pragma unroll
        for (int e = 0; e < 8; ++e) v[e] = cvt((float)v[e] * scale);
        *pp = v;
    }

    // ---- FFN: interleave FFN1 (f-chunks of 32) with FFN2 accumulation ----
    f32x4 acc2[16];
    #pragma unroll
    for (int rt = 0; rt < 16; ++rt) acc2[rt] = (f32x4){0.f, 0.f, 0.f, 0.f};
    {
        bf16x8 bfr[8];
        #pragma unroll
        for (int ks = 0; ks < 8; ++ks)
            bfr[ks] = *(const bf16x8*)(frow + ks * 32 + quad * 8);
        #pragma unroll 1
        for (int k2 = 0; k2 < 16; ++k2) {
            #pragma unroll
            for (int half = 0; half < 2; ++half) {
                int rt1 = k2 * 2 + half;
                f32x4 a1 = {0.f, 0.f, 0.f, 0.f};
                #pragma unroll
                for (int ks = 0; ks < 8; ++ks) {
                    bf16x8 a = *(const bf16x8*)(w1f + ((rt1 * 8 + ks) * 64 + lane) * 8);
                    a1 = mfma16(a, bfr[ks], a1);
                }
                int fb = rt1 * 16 + quad * 4;
                bf16x4 o;
                #pragma unroll
                for (int r = 0; r < 4; ++r) o[r] = cvt(fmaxf(a1[r] + b1[fb + r], 0.f));
                *(bf16x4*)(pw + lid * 72 + half * 16 + quad * 4) = o;   // stage h1 chunk
            }
            bf16x8 bh = *(const bf16x8*)(pw + lid * 72 + quad * 8);
            #pragma unroll
            for (int rt = 0; rt < 16; ++rt) {
                bf16x8 a = *(const bf16x8*)(w2f + ((rt * 16 + k2) * 64 + lane) * 8);
                acc2[rt] = mfma16(a, bh, acc2[rt]);
            }
        }
    }

    // ---- residual + LayerNorm + store ----
    float ps = 0.f, pq = 0.f;
    #pragma unroll
    for (int rt = 0; rt < 16; ++rt) {
        int ob = rt * 16 + quad * 4;
        #pragma unroll
        for (int r = 0; r < 4; ++r) {
            float v = acc2[rt][r] + b2[ob + r] + (float)frow[ob + r];
            acc2[rt][r] = v;
            ps += v;
            pq = fmaf(v, v, pq);
        }
    }
    ps += __shfl_xor(ps, 16); ps += __shfl_xor(ps, 32);
    pq += __shfl_xor(pq, 16); pq += __shfl_xor(pq, 32);
    float mu   = ps * (1.f / 256.f);
    float rstd = rsqrtf(pq * (1.f / 256.f) - mu * mu + 1e-5f);
    float* op = out + baseF + row;
    #pragma unroll
    for (int rt = 0; rt < 16; ++rt) {
        int ob = rt * 16 + quad * 4;
        #pragma unroll
        for (int r = 0; r < 4; ++r) {
            float y = (acc2[rt][r] - mu) * rstd * gam[ob + r] + bet[ob + r];
            op[(size_t)(ob + r) * Nn] = y;
        }
    }
}

// ---------------------------------------------------------------------------
extern "C" void kernel_launch(void* const* d_in, const int* in_sizes, int n_in,
                              void* d_out, int out_size, void* d_ws, size_t ws_size,
                              hipStream_t stream) {
    const float* feature = (const float*)d_in[0];
    const float* bcw     = (const float*)d_in[1];
    const float* wq = (const float*)d_in[2];  const float* bq = (const float*)d_in[3];
    const float* wk = (const float*)d_in[4];  const float* bk = (const float*)d_in[5];
    const float* wv = (const float*)d_in[6];  const float* bv = (const float*)d_in[7];
    const float* wm = (const float*)d_in[8];  const float* bm = (const float*)d_in[9];
    const float* w1 = (const float*)d_in[10]; const float* b1 = (const float*)d_in[11];
    const float* w2 = (const float*)d_in[12]; const float* b2 = (const float*)d_in[13];
    const float* gm = (const float*)d_in[14]; const float* bt = (const float*)d_in[15];

    // workspace layout (~962 KB)
    float*  Kf32 = (float*)d_ws;             // 16384 f32
    float*  Vf32 = Kf32 + 16384;             // 16384 f32
    bf16_t* wqf  = (bf16_t*)(Vf32 + 16384);  // 65536 bf16
    bf16_t* wmf  = wqf + 65536;              // 65536
    bf16_t* w1f  = wmf + 65536;              // 131072
    bf16_t* w2f  = w1f + 131072;             // 131072
    bf16_t* Kf   = w2f + 131072;             // 16384
    bf16_t* Vf   = Kf + 16384;               // 16384
    float*  bqp  = (float*)(Vf + 16384);     // 256 f32

    float* op = (float*)d_out;

    hipLaunchKernelGGL(kv_kernel, dim3(Cc), dim3(Mm), 0, stream,
                       wk, bk, wv, bv, bcw, Kf32, Vf32);
    hipLaunchKernelGGL(pack_kernel, dim3((426240 + 255) / 256), dim3(256), 0, stream,
                       wq, bq, wm, w1, w2, Kf32, Vf32,
                       wqf, wmf, w1f, w2f, Kf, Vf, bqp);
    hipLaunchKernelGGL(sfta_mfma, dim3(NTB, Bc), dim3(256), 0, stream,
                       feature, wqf, bqp, wmf, bm, w1f, b1, w2f, b2,
                       Kf, Vf, gm, bt, op);
}